// Round 12
// baseline (302.354 us; speedup 1.0000x reference)
//
#include <hip/hip_runtime.h>
#include <cstdint>
#include <cstddef>

#define Bc 4
#define Tc 2048
#define Cc 1024
#define Hc 16
#define Dc 64

typedef unsigned short ushort_t;
typedef __bf16 v8bf __attribute__((ext_vector_type(8)));
typedef float v4f __attribute__((ext_vector_type(4)));

__device__ inline ushort_t f2bf(float f) {
  union { float f; unsigned int u; } v; v.f = f;
  unsigned int r = v.u + 0x7fffu + ((v.u >> 16) & 1u);  // RNE
  return (ushort_t)(r >> 16);
}

__device__ inline unsigned int pack2bf(float lo, float hi) {
  return (unsigned int)f2bf(lo) | ((unsigned int)f2bf(hi) << 16);
}

// async global->LDS, 16B per lane. LDS dest: wave-uniform base; HW adds lane*16.
__device__ inline void gl_lds16(const void* g, void* l) {
  __builtin_amdgcn_global_load_lds((__attribute__((address_space(1))) void*)g,
                                   (__attribute__((address_space(3))) void*)l,
                                   16, 0, 0);
}

// float -> bf16 elementwise
__global__ void cvt_bf16(const float* __restrict__ in, ushort_t* __restrict__ out, int n) {
  int i = blockIdx.x * blockDim.x + threadIdx.x;
  if (i < n) out[i] = f2bf(in[i]);
}

// w [K,N] f32 -> wt [N,K] bf16, tiled via LDS (coalesced both sides)
__global__ __launch_bounds__(256) void transpose_bf16t(const float* __restrict__ w,
                                                       ushort_t* __restrict__ wt,
                                                       int K, int N) {
  __shared__ float tile[64][65];
  const int t = threadIdx.x;
  const int n0 = blockIdx.x * 64;
  const int k0 = blockIdx.y * 64;
  #pragma unroll
  for (int i = 0; i < 16; ++i) {
    int r = (t >> 6) + i * 4, c = t & 63;
    tile[r][c] = w[(size_t)(k0 + r) * N + n0 + c];
  }
  __syncthreads();
  #pragma unroll
  for (int i = 0; i < 16; ++i) {
    int r = (t >> 6) + i * 4, c = t & 63;
    wt[(size_t)(n0 + r) * K + k0 + c] = f2bf(tile[c][r]);
  }
}

// m97-style 128x128 GEMM, BK=32, 4 waves, global_load_lds staging, 2-phase
// double-buffered K-loop. ROUND-9 VERIFIED VERSION (85 us qkv, 606 TF = the
// documented 2-phase structural ceiling; the 8-phase 256^2 port regressed to
// 94.5 us at 1 block/CU with 1.5 grid epochs — reverted per falsifier).
// C = A[M,K] * BT[N,K]^T + bias.
// MODE 0: fp32 C[M,N].
// MODE 1: qkv epilogue, two-pass LDS staging: Q/K stage 64 m-rows per pass
//         ([64][136]); V stages transposed [128][72] with 64 m-cols per pass.
//         Coalesced uint4 stores: Q/K as [bh,t,d] rows, V as [bh,d,t] rows.
template <int MODE>
__global__ __launch_bounds__(256) void gemm128(const ushort_t* __restrict__ A,
                                               const ushort_t* __restrict__ BT,
                                               const float* __restrict__ bias,
                                               float* __restrict__ Cout,
                                               ushort_t* __restrict__ Qb,
                                               ushort_t* __restrict__ Kb,
                                               ushort_t* __restrict__ Vt,
                                               int M, int N, int K) {
  // 2 buffers x (As 8192 B + Bs 8192 B). MODE1 epilogue (18432 B) reuses [0,18432).
  __shared__ __align__(16) unsigned char smem[32768];

  const int t = threadIdx.x;
  const int wave = t >> 6;
  const int lane = t & 63;
  const int quad = lane >> 4;
  const int l15 = lane & 15;
  const int m0 = blockIdx.y * 128;
  const int n0 = blockIdx.x * 128;
  const int wm = wave >> 1, wn = wave & 1;

  v4f acc[4][4];
  #pragma unroll
  for (int mi = 0; mi < 4; ++mi)
    #pragma unroll
    for (int ni = 0; ni < 4; ++ni) acc[mi][ni] = (v4f){0.f, 0.f, 0.f, 0.f};

  const int NK = K >> 5;

  const int srow0 = t >> 2, ssc = (t & 3) * 8;
  const int srow1 = (t + 256) >> 2;
  const int sbase0 = (t & ~63) * 8;
  const int sbase1 = ((t & ~63) + 256) * 8;

  {
    ushort_t* As = (ushort_t*)smem;
    ushort_t* Bs = (ushort_t*)(smem + 8192);
    gl_lds16(A + (size_t)(m0 + srow0) * K + ssc, &As[sbase0]);
    gl_lds16(BT + (size_t)(n0 + srow0) * K + ssc, &Bs[sbase0]);
    gl_lds16(A + (size_t)(m0 + srow1) * K + ssc, &As[sbase1]);
    gl_lds16(BT + (size_t)(n0 + srow1) * K + ssc, &Bs[sbase1]);
  }

  for (int kk = 0; kk < NK; ++kk) {
    const int bi = kk & 1;
    __syncthreads();   // staging of buf[bi] drained; all reads of buf[bi^1] done
    if (kk + 1 < NK) {
      const int kc = (kk + 1) * 32;
      ushort_t* As = (ushort_t*)(smem + (bi ^ 1) * 16384);
      ushort_t* Bs = (ushort_t*)(smem + (bi ^ 1) * 16384 + 8192);
      gl_lds16(A + (size_t)(m0 + srow0) * K + kc + ssc, &As[sbase0]);
      gl_lds16(BT + (size_t)(n0 + srow0) * K + kc + ssc, &Bs[sbase0]);
      gl_lds16(A + (size_t)(m0 + srow1) * K + kc + ssc, &As[sbase1]);
      gl_lds16(BT + (size_t)(n0 + srow1) * K + kc + ssc, &Bs[sbase1]);
    }

    const ushort_t* As = (const ushort_t*)(smem + bi * 16384);
    const ushort_t* Bs = (const ushort_t*)(smem + bi * 16384 + 8192);
    v8bf a[4], b[4];
    #pragma unroll
    for (int mi = 0; mi < 4; ++mi)
      a[mi] = *reinterpret_cast<const v8bf*>(&As[(wm * 64 + mi * 16 + l15) * 32 + quad * 8]);
    #pragma unroll
    for (int ni = 0; ni < 4; ++ni)
      b[ni] = *reinterpret_cast<const v8bf*>(&Bs[(wn * 64 + ni * 16 + l15) * 32 + quad * 8]);
    #pragma unroll
    for (int mi = 0; mi < 4; ++mi)
      #pragma unroll
      for (int ni = 0; ni < 4; ++ni)
        acc[mi][ni] = __builtin_amdgcn_mfma_f32_16x16x32_bf16(a[mi], b[ni], acc[mi][ni], 0, 0, 0);
  }
  __syncthreads();   // all reads done; MODE1 may reuse smem for Cs

  // Epilogue. C/D layout: col = lane&15, row = quad*4 + i.
  if (MODE == 0) {
    #pragma unroll
    for (int ni = 0; ni < 4; ++ni) {
      const int n_g = n0 + wn * 64 + ni * 16 + l15;
      const float bv = bias[n_g];
      #pragma unroll
      for (int mi = 0; mi < 4; ++mi)
        #pragma unroll
        for (int i = 0; i < 4; ++i) {
          int m_g = m0 + wm * 64 + mi * 16 + quad * 4 + i;
          Cout[(size_t)m_g * N + n_g] = acc[mi][ni][i] + bv;
        }
    }
  } else {
    const int part = n0 >> 10;          // block-uniform: 0:Q 1:K 2:V
    ushort_t* Cs = (ushort_t*)smem;
    if (part < 2) {
      // two passes of 64 m-rows through [64][136] staging -> [bh,t,d] rows
      ushort_t* dst = (part == 0) ? Qb : Kb;
      #pragma unroll
      for (int p = 0; p < 2; ++p) {
        if (wm == p) {
          #pragma unroll
          for (int ni = 0; ni < 4; ++ni) {
            const int n_l = wn * 64 + ni * 16 + l15;
            const float bv = bias[n0 + n_l];
            #pragma unroll
            for (int mi = 0; mi < 4; ++mi)
              #pragma unroll
              for (int i = 0; i < 4; ++i) {
                int r = mi * 16 + quad * 4 + i;       // local row 0..63
                Cs[r * 136 + n_l] = f2bf(acc[mi][ni][i] + bv);
              }
          }
        }
        __syncthreads();
        const int r = t >> 2, q4 = t & 3;             // 64 rows x 4 quarters
        const int m_g = m0 + p * 64 + r;
        const int bb = m_g >> 11, tt = m_g & 2047;
        const int h = ((n0 & 1023) >> 6) + (q4 >> 1);
        ushort_t* gp = dst + (((size_t)bb * Hc + h) * Tc + tt) * Dc + (q4 & 1) * 32;
        const ushort_t* sp = &Cs[r * 136 + q4 * 32];
        #pragma unroll
        for (int j = 0; j < 4; ++j)
          *reinterpret_cast<uint4*>(gp + j * 8) = *reinterpret_cast<const uint4*>(sp + j * 8);
        __syncthreads();
      }
    } else {
      // V: two passes of 64 m-cols through transposed [128][72] staging
      // -> [bh,d,t] rows
      #pragma unroll
      for (int p = 0; p < 2; ++p) {
        if (wm == p) {
          #pragma unroll
          for (int ni = 0; ni < 4; ++ni) {
            const int n_l = wn * 64 + ni * 16 + l15;
            const float bv = bias[n0 + n_l];
            #pragma unroll
            for (int mi = 0; mi < 4; ++mi)
              #pragma unroll
              for (int i = 0; i < 4; ++i) {
                int c = mi * 16 + quad * 4 + i;       // local m col 0..63
                Cs[n_l * 72 + c] = f2bf(acc[mi][ni][i] + bv);
              }
          }
        }
        __syncthreads();
        const int bb = m0 >> 11, tt0 = m0 & 2047;
        const int h0 = (n0 >> 6) - 32;               // (n0-2048)/64
        const int row = t >> 1, half = t & 1;        // row = n_l
        const int d = row & 63, hh = row >> 6;
        ushort_t* gp = Vt + ((size_t)(bb * Hc + h0 + hh) * Dc + d) * Tc +
                       tt0 + p * 64 + half * 32;
        const ushort_t* sp = &Cs[row * 72 + half * 32];
        #pragma unroll
        for (int j = 0; j < 4; ++j)
          *reinterpret_cast<uint4*>(gp + j * 8) = *reinterpret_cast<const uint4*>(sp + j * 8);
        __syncthreads();
      }
    }
  }
}

// One q-tile slab of flash attention (v10 structure) with the LDS P-transform
// (verified rounds 9/11): P written to per-wave scratch (XOR-swizzled
// ds_write_b64) and read back as PV B-fragments (2x ds_read_b128).
__device__ __forceinline__ void flash_body(int jq, int bh, int w, int lane, int quad, int l15,
                                           const ushort_t* __restrict__ Qb,
                                           const ushort_t* __restrict__ Kb,
                                           const ushort_t* __restrict__ Vt,
                                           ushort_t* __restrict__ yb,
                                           ushort_t (*Kbuf)[8 * 512],
                                           ushort_t (*Vbuf)[8 * 512],
                                           ushort_t* __restrict__ Ps) {
  const int ktmax = jq;                        // diag tile index
  const int s = jq * 64 + w * 16;              // this wave's 16 queries

  const ushort_t* Kbh = Kb + (size_t)bh * (Tc * Dc);
  const ushort_t* Vbh = Vt + (size_t)bh * (Dc * Tc);

  const ushort_t* qp = Qb + ((size_t)bh * Tc + s + l15) * Dc;
  v8bf q0 = *reinterpret_cast<const v8bf*>(qp + quad * 8);
  v8bf q1 = *reinterpret_cast<const v8bf*>(qp + 32 + quad * 8);

  v4f O[4];
  #pragma unroll
  for (int i = 0; i < 4; ++i) O[i] = (v4f){0.f, 0.f, 0.f, 0.f};
  float ps = 0.f;
  const float SCALE_LOG2E = 0.125f * 1.44269504f;

  const int swz = (l15 & 7) << 3;
  const int prow = l15 * 64;

  #pragma unroll
  for (int it = 0; it < 2; ++it) {
    int c = w + it * 4, nt = c >> 1, ks = c & 1;
    gl_lds16(Kbh + (size_t)(nt * 16 + l15) * Dc + ks * 32 + quad * 8, &Kbuf[0][c * 512]);
    gl_lds16(Vbh + (size_t)(nt * 16 + l15) * Tc + ks * 32 + quad * 8, &Vbuf[0][c * 512]);
  }

  for (int kt = 0; kt <= ktmax; ++kt) {
    __syncthreads();
    const int cur = kt & 1;
    if (kt < ktmax) {
      const int nxt = cur ^ 1;
      #pragma unroll
      for (int it = 0; it < 2; ++it) {
        int c = w + it * 4, nt = c >> 1, ks = c & 1;
        gl_lds16(Kbh + (size_t)((kt + 1) * 64 + nt * 16 + l15) * Dc + ks * 32 + quad * 8,
                 &Kbuf[nxt][c * 512]);
        gl_lds16(Vbh + (size_t)(nt * 16 + l15) * Tc + (kt + 1) * 64 + ks * 32 + quad * 8,
                 &Vbuf[nxt][c * 512]);
      }
    }

    const bool diag = (kt == ktmax);

    v4f st[4];
    #pragma unroll
    for (int nt = 0; nt < 4; ++nt) {
      v8bf k0 = *reinterpret_cast<const v8bf*>(&Kbuf[cur][(nt * 2 + 0) * 512 + lane * 8]);
      v8bf k1 = *reinterpret_cast<const v8bf*>(&Kbuf[cur][(nt * 2 + 1) * 512 + lane * 8]);
      st[nt] = (v4f){0.f, 0.f, 0.f, 0.f};
      st[nt] = __builtin_amdgcn_mfma_f32_16x16x32_bf16(k0, q0, st[nt], 0, 0, 0);
      st[nt] = __builtin_amdgcn_mfma_f32_16x16x32_bf16(k1, q1, st[nt], 0, 0, 0);
    }

    #pragma unroll
    for (int nt = 0; nt < 4; ++nt) {
      uint2 pw;
      if (diag && nt > w) { pw.x = 0u; pw.y = 0u; }
      else {
        float p[4];
        #pragma unroll
        for (int i = 0; i < 4; ++i) {
          float e = __builtin_amdgcn_exp2f(st[nt][i] * SCALE_LOG2E);
          p[i] = (diag && nt == w && quad * 4 + i > l15) ? 0.f : e;
          ps += p[i];
        }
        pw.x = pack2bf(p[0], p[1]);
        pw.y = pack2bf(p[2], p[3]);
      }
      *reinterpret_cast<uint2*>(&Ps[(prow + nt * 16 + quad * 4) ^ swz]) = pw;
    }

    const int kslim = (diag && w < 2) ? 1 : 2;
    #pragma unroll
    for (int ks = 0; ks < 2; ++ks) {
      if (ks >= kslim) continue;
      v8bf pb = *reinterpret_cast<const v8bf*>(&Ps[(prow + ks * 32 + quad * 8) ^ swz]);
      #pragma unroll
      for (int dt = 0; dt < 4; ++dt) {
        v8bf vf = *reinterpret_cast<const v8bf*>(&Vbuf[cur][(dt * 2 + ks) * 512 + lane * 8]);
        O[dt] = __builtin_amdgcn_mfma_f32_16x16x32_bf16(vf, pb, O[dt], 0, 0, 0);
      }
    }
  }

  ps += __shfl_xor(ps, 16);
  ps += __shfl_xor(ps, 32);
  const float inv = 1.f / ps;

  const int bb = bh >> 4, h = bh & 15;
  ushort_t* yp = yb + ((size_t)bb * Tc + s + l15) * Cc + h * Dc + quad * 4;
  #pragma unroll
  for (int dt = 0; dt < 4; ++dt) {
    uint2 pa;
    pa.x = pack2bf(O[dt][0] * inv, O[dt][1] * inv);
    pa.y = pack2bf(O[dt][2] * inv, O[dt][3] * inv);
    *reinterpret_cast<uint2*>(yp + dt * 16) = pa;
  }
}

// MFMA flash attention v13 = v12 (verified rounds 9/11: balanced sequential
// pairing, 1024 blocks = 4/CU, uniform 33 iters, LDS P-transform) + XCD-AWARE
// BLOCK SWIZZLE (T1). 1-D grid of 1024; hardware round-robins dispatch index
// over the 8 XCDs, so swz = (bid&7)*128 + (bid>>3) gives each XCD a contiguous
// 128-block chunk = 8 bh values. Per-XCD K/V working set = 8 bh x 512 KB =
// 4 MB = exactly one XCD L2 (was 64 bh = 32 MB -> thrash -> 195 MB HBM fetch).
// Bijective since 1024 % 8 == 0; blocks are uniform-duration so the remap has
// no load-balance side effects.
__global__ __launch_bounds__(256, 4) void flash_mfma13(const ushort_t* __restrict__ Qb,
                                                       const ushort_t* __restrict__ Kb,
                                                       const ushort_t* __restrict__ Vt,
                                                       ushort_t* __restrict__ yb) {
  const int bid = blockIdx.x;                  // 0..1023
  const int swz = (bid & 7) * 128 + (bid >> 3);
  const int x = swz & 15;                      // q-tile pair index 0..15
  const int bh = swz >> 4;                     // head 0..63 (8 per XCD chunk)
  const int jqA = 31 - x;                      // long item: 31..16
  const int jqB = x;                           // short item: 0..15
  const int t = threadIdx.x;
  const int w = t >> 6;
  const int lane = t & 63;
  const int quad = lane >> 4;
  const int l15 = lane & 15;

  __shared__ __align__(16) ushort_t Kbuf[2][8 * 512];   // 8 chunks x 1KiB, x2
  __shared__ __align__(16) ushort_t Vbuf[2][8 * 512];
  __shared__ __align__(16) ushort_t Pbuf[4][1024];      // per-wave 2KB P scratch

  flash_body(jqA, bh, w, lane, quad, l15, Qb, Kb, Vt, yb, Kbuf, Vbuf, &Pbuf[w][0]);
  __syncthreads();   // item A fully done with LDS before item B's prologue writes
  flash_body(jqB, bh, w, lane, quad, l15, Qb, Kb, Vt, yb, Kbuf, Vbuf, &Pbuf[w][0]);
}

extern "C" void kernel_launch(void* const* d_in, const int* in_sizes, int n_in,
                              void* d_out, int out_size, void* d_ws, size_t ws_size,
                              hipStream_t stream) {
  const float* x      = (const float*)d_in[0];   // [B,T,C]
  const float* w_attn = (const float*)d_in[1];   // [C,3C]
  const float* b_attn = (const float*)d_in[2];   // [3C]
  const float* w_proj = (const float*)d_in[3];   // [C,C]
  const float* b_proj = (const float*)d_in[4];   // [C]
  float* out = (float*)d_out;                    // [B,T,C] fp32

  const int M = Bc * Tc;        // 8192
  const int K = Cc;             // 1024
  const int N_qkv = 3 * Cc;     // 3072

  ushort_t* xb     = (ushort_t*)d_ws;                     // M*K        (16 MB)
  ushort_t* wattnT = xb + (size_t)M * K;                  // 3C*C       (6 MB)
  ushort_t* wprojT = wattnT + (size_t)N_qkv * K;          // C*C        (2 MB)
  ushort_t* Qb     = wprojT + (size_t)Cc * Cc;            // [bh,t,d]   (16 MB)
  ushort_t* Kb     = Qb + (size_t)M * Cc;                 // [bh,t,d]   (16 MB)
  ushort_t* Vt     = Kb + (size_t)M * Cc;                 // [bh,d,t]   (16 MB)
  ushort_t* yb     = Vt + (size_t)M * Cc;                 // [m,C]      (16 MB)

  int nx = M * K;
  cvt_bf16<<<(nx + 255) / 256, 256, 0, stream>>>(x, xb, nx);
  transpose_bf16t<<<dim3(N_qkv / 64, K / 64), 256, 0, stream>>>(w_attn, wattnT, K, N_qkv);
  transpose_bf16t<<<dim3(Cc / 64, K / 64), 256, 0, stream>>>(w_proj, wprojT, K, Cc);

  // qkv = x @ w_attn + b_attn  -> Qb/Kb ([bh,t,d]) and Vt ([bh,d,t]) bf16
  gemm128<1><<<dim3(N_qkv / 128, M / 128), 256, 0, stream>>>(
      xb, wattnT, b_attn, nullptr, Qb, Kb, Vt, M, N_qkv, K);

  // y = softmax(QK^T/sqrt(D)) V  (balanced pairing + LDS P-transform +
  // XCD-aware swizzle; 1-D grid for swizzle control)
  flash_mfma13<<<dim3(1024), 256, 0, stream>>>(Qb, Kb, Vt, yb);

  // out = y @ w_proj + b_proj   (fp32 out, 2-phase 128x128)
  gemm128<0><<<dim3(Cc / 128, M / 128), 256, 0, stream>>>(
      yb, wprojT, b_proj, out, nullptr, nullptr, nullptr, M, Cc, K);
}

// Round 13
// 273.283 us; speedup vs baseline: 1.1064x; 1.1064x over previous
//
#include <hip/hip_runtime.h>
#include <cstdint>
#include <cstddef>

#define Bc 4
#define Tc 2048
#define Cc 1024
#define Hc 16
#define Dc 64

typedef unsigned short ushort_t;
typedef __bf16 v8bf __attribute__((ext_vector_type(8)));
typedef float v4f __attribute__((ext_vector_type(4)));

// hardware RNE f32->bf16 (compiler emits native v_cvt)
__device__ inline ushort_t f2bf(float f) {
  union { __bf16 b; ushort_t u; } v;
  v.b = (__bf16)f;
  return v.u;
}

// two f32 -> packed 2x bf16 in ONE instruction (T12 recipe; no builtin exists)
__device__ inline unsigned int pack2bf(float lo, float hi) {
  unsigned int r;
  asm("v_cvt_pk_bf16_f32 %0, %1, %2" : "=v"(r) : "v"(lo), "v"(hi));
  return r;
}

// async global->LDS, 16B per lane. LDS dest: wave-uniform base; HW adds lane*16.
__device__ inline void gl_lds16(const void* g, void* l) {
  __builtin_amdgcn_global_load_lds((__attribute__((address_space(1))) void*)g,
                                   (__attribute__((address_space(3))) void*)l,
                                   16, 0, 0);
}

// float -> bf16 elementwise, 8 elems/thread (G13: vectorized loads/stores)
__global__ void cvt_bf16(const float* __restrict__ in, ushort_t* __restrict__ out, int n) {
  int base = (blockIdx.x * blockDim.x + threadIdx.x) * 8;
  if (base < n) {
    float4 f0 = *reinterpret_cast<const float4*>(in + base);
    float4 f1 = *reinterpret_cast<const float4*>(in + base + 4);
    uint4 r;
    r.x = pack2bf(f0.x, f0.y);
    r.y = pack2bf(f0.z, f0.w);
    r.z = pack2bf(f1.x, f1.y);
    r.w = pack2bf(f1.z, f1.w);
    *reinterpret_cast<uint4*>(out + base) = r;
  }
}

// w [K,N] f32 -> wt [N,K] bf16, tiled via LDS (coalesced both sides)
__global__ __launch_bounds__(256) void transpose_bf16t(const float* __restrict__ w,
                                                       ushort_t* __restrict__ wt,
                                                       int K, int N) {
  __shared__ float tile[64][65];
  const int t = threadIdx.x;
  const int n0 = blockIdx.x * 64;
  const int k0 = blockIdx.y * 64;
  #pragma unroll
  for (int i = 0; i < 16; ++i) {
    int r = (t >> 6) + i * 4, c = t & 63;
    tile[r][c] = w[(size_t)(k0 + r) * N + n0 + c];
  }
  __syncthreads();
  #pragma unroll
  for (int i = 0; i < 16; ++i) {
    int r = (t >> 6) + i * 4, c = t & 63;
    wt[(size_t)(n0 + r) * K + k0 + c] = f2bf(tile[c][r]);
  }
}

// m97-style 128x128 GEMM, BK=32, 4 waves, global_load_lds staging, 2-phase
// double-buffered K-loop (ROUND-9 VERIFIED; 606 TF qkv = documented 2-phase
// structural ceiling; both the B-register bypass and the 8-phase 256^2 port
// regressed and were reverted per falsifiers).
// C = A[M,K] * BT[N,K]^T + bias.
// MODE 0: fp32 C[M,N].
// MODE 1: qkv epilogue, two-pass LDS staging: Q/K stage 64 m-rows per pass
//         ([64][136]); V stages transposed [128][72] with 64 m-cols per pass.
//         Coalesced uint4 stores: Q/K as [bh,t,d] rows, V as [bh,d,t] rows.
template <int MODE>
__global__ __launch_bounds__(256) void gemm128(const ushort_t* __restrict__ A,
                                               const ushort_t* __restrict__ BT,
                                               const float* __restrict__ bias,
                                               float* __restrict__ Cout,
                                               ushort_t* __restrict__ Qb,
                                               ushort_t* __restrict__ Kb,
                                               ushort_t* __restrict__ Vt,
                                               int M, int N, int K) {
  // 2 buffers x (As 8192 B + Bs 8192 B). MODE1 epilogue (18432 B) reuses [0,18432).
  __shared__ __align__(16) unsigned char smem[32768];

  const int t = threadIdx.x;
  const int wave = t >> 6;
  const int lane = t & 63;
  const int quad = lane >> 4;
  const int l15 = lane & 15;
  const int m0 = blockIdx.y * 128;
  const int n0 = blockIdx.x * 128;
  const int wm = wave >> 1, wn = wave & 1;

  v4f acc[4][4];
  #pragma unroll
  for (int mi = 0; mi < 4; ++mi)
    #pragma unroll
    for (int ni = 0; ni < 4; ++ni) acc[mi][ni] = (v4f){0.f, 0.f, 0.f, 0.f};

  const int NK = K >> 5;

  const int srow0 = t >> 2, ssc = (t & 3) * 8;
  const int srow1 = (t + 256) >> 2;
  const int sbase0 = (t & ~63) * 8;
  const int sbase1 = ((t & ~63) + 256) * 8;

  {
    ushort_t* As = (ushort_t*)smem;
    ushort_t* Bs = (ushort_t*)(smem + 8192);
    gl_lds16(A + (size_t)(m0 + srow0) * K + ssc, &As[sbase0]);
    gl_lds16(BT + (size_t)(n0 + srow0) * K + ssc, &Bs[sbase0]);
    gl_lds16(A + (size_t)(m0 + srow1) * K + ssc, &As[sbase1]);
    gl_lds16(BT + (size_t)(n0 + srow1) * K + ssc, &Bs[sbase1]);
  }

  for (int kk = 0; kk < NK; ++kk) {
    const int bi = kk & 1;
    __syncthreads();   // staging of buf[bi] drained; all reads of buf[bi^1] done
    if (kk + 1 < NK) {
      const int kc = (kk + 1) * 32;
      ushort_t* As = (ushort_t*)(smem + (bi ^ 1) * 16384);
      ushort_t* Bs = (ushort_t*)(smem + (bi ^ 1) * 16384 + 8192);
      gl_lds16(A + (size_t)(m0 + srow0) * K + kc + ssc, &As[sbase0]);
      gl_lds16(BT + (size_t)(n0 + srow0) * K + kc + ssc, &Bs[sbase0]);
      gl_lds16(A + (size_t)(m0 + srow1) * K + kc + ssc, &As[sbase1]);
      gl_lds16(BT + (size_t)(n0 + srow1) * K + kc + ssc, &Bs[sbase1]);
    }

    const ushort_t* As = (const ushort_t*)(smem + bi * 16384);
    const ushort_t* Bs = (const ushort_t*)(smem + bi * 16384 + 8192);
    v8bf a[4], b[4];
    #pragma unroll
    for (int mi = 0; mi < 4; ++mi)
      a[mi] = *reinterpret_cast<const v8bf*>(&As[(wm * 64 + mi * 16 + l15) * 32 + quad * 8]);
    #pragma unroll
    for (int ni = 0; ni < 4; ++ni)
      b[ni] = *reinterpret_cast<const v8bf*>(&Bs[(wn * 64 + ni * 16 + l15) * 32 + quad * 8]);
    #pragma unroll
    for (int mi = 0; mi < 4; ++mi)
      #pragma unroll
      for (int ni = 0; ni < 4; ++ni)
        acc[mi][ni] = __builtin_amdgcn_mfma_f32_16x16x32_bf16(a[mi], b[ni], acc[mi][ni], 0, 0, 0);
  }
  __syncthreads();   // all reads done; MODE1 may reuse smem for Cs

  // Epilogue. C/D layout: col = lane&15, row = quad*4 + i.
  if (MODE == 0) {
    #pragma unroll
    for (int ni = 0; ni < 4; ++ni) {
      const int n_g = n0 + wn * 64 + ni * 16 + l15;
      const float bv = bias[n_g];
      #pragma unroll
      for (int mi = 0; mi < 4; ++mi)
        #pragma unroll
        for (int i = 0; i < 4; ++i) {
          int m_g = m0 + wm * 64 + mi * 16 + quad * 4 + i;
          Cout[(size_t)m_g * N + n_g] = acc[mi][ni][i] + bv;
        }
    }
  } else {
    const int part = n0 >> 10;          // block-uniform: 0:Q 1:K 2:V
    ushort_t* Cs = (ushort_t*)smem;
    if (part < 2) {
      // two passes of 64 m-rows through [64][136] staging -> [bh,t,d] rows
      ushort_t* dst = (part == 0) ? Qb : Kb;
      #pragma unroll
      for (int p = 0; p < 2; ++p) {
        if (wm == p) {
          #pragma unroll
          for (int ni = 0; ni < 4; ++ni) {
            const int n_l = wn * 64 + ni * 16 + l15;
            const float bv = bias[n0 + n_l];
            #pragma unroll
            for (int mi = 0; mi < 4; ++mi)
              #pragma unroll
              for (int i = 0; i < 4; ++i) {
                int r = mi * 16 + quad * 4 + i;       // local row 0..63
                Cs[r * 136 + n_l] = f2bf(acc[mi][ni][i] + bv);
              }
          }
        }
        __syncthreads();
        const int r = t >> 2, q4 = t & 3;             // 64 rows x 4 quarters
        const int m_g = m0 + p * 64 + r;
        const int bb = m_g >> 11, tt = m_g & 2047;
        const int h = ((n0 & 1023) >> 6) + (q4 >> 1);
        ushort_t* gp = dst + (((size_t)bb * Hc + h) * Tc + tt) * Dc + (q4 & 1) * 32;
        const ushort_t* sp = &Cs[r * 136 + q4 * 32];
        #pragma unroll
        for (int j = 0; j < 4; ++j)
          *reinterpret_cast<uint4*>(gp + j * 8) = *reinterpret_cast<const uint4*>(sp + j * 8);
        __syncthreads();
      }
    } else {
      // V: two passes of 64 m-cols through transposed [128][72] staging
      // -> [bh,d,t] rows
      #pragma unroll
      for (int p = 0; p < 2; ++p) {
        if (wm == p) {
          #pragma unroll
          for (int ni = 0; ni < 4; ++ni) {
            const int n_l = wn * 64 + ni * 16 + l15;
            const float bv = bias[n0 + n_l];
            #pragma unroll
            for (int mi = 0; mi < 4; ++mi)
              #pragma unroll
              for (int i = 0; i < 4; ++i) {
                int c = mi * 16 + quad * 4 + i;       // local m col 0..63
                Cs[n_l * 72 + c] = f2bf(acc[mi][ni][i] + bv);
              }
          }
        }
        __syncthreads();
        const int bb = m0 >> 11, tt0 = m0 & 2047;
        const int h0 = (n0 >> 6) - 32;               // (n0-2048)/64
        const int row = t >> 1, half = t & 1;        // row = n_l
        const int d = row & 63, hh = row >> 6;
        ushort_t* gp = Vt + ((size_t)(bb * Hc + h0 + hh) * Dc + d) * Tc +
                       tt0 + p * 64 + half * 32;
        const ushort_t* sp = &Cs[row * 72 + half * 32];
        #pragma unroll
        for (int j = 0; j < 4; ++j)
          *reinterpret_cast<uint4*>(gp + j * 8) = *reinterpret_cast<const uint4*>(sp + j * 8);
        __syncthreads();
      }
    }
  }
}

// One q-tile slab of flash attention (v10 structure) with the LDS P-transform
// (verified rounds 9/11/12): P written to per-wave scratch (XOR-swizzled
// ds_write_b64) and read back as PV B-fragments (2x ds_read_b128). pack2bf is
// now a single v_cvt_pk_bf16_f32 (was ~11 VALU ops) — flash's top pipe was
// VALU at 38.5% busy.
__device__ __forceinline__ void flash_body(int jq, int bh, int w, int lane, int quad, int l15,
                                           const ushort_t* __restrict__ Qb,
                                           const ushort_t* __restrict__ Kb,
                                           const ushort_t* __restrict__ Vt,
                                           ushort_t* __restrict__ yb,
                                           ushort_t (*Kbuf)[8 * 512],
                                           ushort_t (*Vbuf)[8 * 512],
                                           ushort_t* __restrict__ Ps) {
  const int ktmax = jq;                        // diag tile index
  const int s = jq * 64 + w * 16;              // this wave's 16 queries

  const ushort_t* Kbh = Kb + (size_t)bh * (Tc * Dc);
  const ushort_t* Vbh = Vt + (size_t)bh * (Dc * Tc);

  const ushort_t* qp = Qb + ((size_t)bh * Tc + s + l15) * Dc;
  v8bf q0 = *reinterpret_cast<const v8bf*>(qp + quad * 8);
  v8bf q1 = *reinterpret_cast<const v8bf*>(qp + 32 + quad * 8);

  v4f O[4];
  #pragma unroll
  for (int i = 0; i < 4; ++i) O[i] = (v4f){0.f, 0.f, 0.f, 0.f};
  float ps = 0.f;
  const float SCALE_LOG2E = 0.125f * 1.44269504f;

  const int swz = (l15 & 7) << 3;
  const int prow = l15 * 64;

  #pragma unroll
  for (int it = 0; it < 2; ++it) {
    int c = w + it * 4, nt = c >> 1, ks = c & 1;
    gl_lds16(Kbh + (size_t)(nt * 16 + l15) * Dc + ks * 32 + quad * 8, &Kbuf[0][c * 512]);
    gl_lds16(Vbh + (size_t)(nt * 16 + l15) * Tc + ks * 32 + quad * 8, &Vbuf[0][c * 512]);
  }

  for (int kt = 0; kt <= ktmax; ++kt) {
    __syncthreads();   // staging of buf[kt&1] drained; all waves past compute(kt-1)
    const int cur = kt & 1;
    if (kt < ktmax) {
      const int nxt = cur ^ 1;
      #pragma unroll
      for (int it = 0; it < 2; ++it) {
        int c = w + it * 4, nt = c >> 1, ks = c & 1;
        gl_lds16(Kbh + (size_t)((kt + 1) * 64 + nt * 16 + l15) * Dc + ks * 32 + quad * 8,
                 &Kbuf[nxt][c * 512]);
        gl_lds16(Vbh + (size_t)(nt * 16 + l15) * Tc + (kt + 1) * 64 + ks * 32 + quad * 8,
                 &Vbuf[nxt][c * 512]);
      }
    }

    const bool diag = (kt == ktmax);

    // ---- S^T = K Q^T ----
    v4f st[4];
    #pragma unroll
    for (int nt = 0; nt < 4; ++nt) {
      v8bf k0 = *reinterpret_cast<const v8bf*>(&Kbuf[cur][(nt * 2 + 0) * 512 + lane * 8]);
      v8bf k1 = *reinterpret_cast<const v8bf*>(&Kbuf[cur][(nt * 2 + 1) * 512 + lane * 8]);
      st[nt] = (v4f){0.f, 0.f, 0.f, 0.f};
      st[nt] = __builtin_amdgcn_mfma_f32_16x16x32_bf16(k0, q0, st[nt], 0, 0, 0);
      st[nt] = __builtin_amdgcn_mfma_f32_16x16x32_bf16(k1, q1, st[nt], 0, 0, 0);
    }

    // ---- exp2 + causal mask -> P rows in per-wave LDS scratch ----
    // S^T element (nt,i): q = l15 (col), kv = nt*16 + quad*4 + i (row).
    // relative q position within diag tile is w*16: s - ktmax*64 = w*16.
    #pragma unroll
    for (int nt = 0; nt < 4; ++nt) {
      uint2 pw;
      if (diag && nt > w) { pw.x = 0u; pw.y = 0u; }
      else {
        float p[4];
        #pragma unroll
        for (int i = 0; i < 4; ++i) {
          float e = __builtin_amdgcn_exp2f(st[nt][i] * SCALE_LOG2E);
          p[i] = (diag && nt == w && quad * 4 + i > l15) ? 0.f : e;
          ps += p[i];
        }
        pw.x = pack2bf(p[0], p[1]);
        pw.y = pack2bf(p[2], p[3]);
      }
      *reinterpret_cast<uint2*>(&Ps[(prow + nt * 16 + quad * 4) ^ swz]) = pw;
    }

    // ---- O^T += V^T P^T ; P B-fragment read directly from scratch ----
    const int kslim = (diag && w < 2) ? 1 : 2;
    #pragma unroll
    for (int ks = 0; ks < 2; ++ks) {
      if (ks >= kslim) continue;          // wave-uniform
      v8bf pb = *reinterpret_cast<const v8bf*>(&Ps[(prow + ks * 32 + quad * 8) ^ swz]);
      #pragma unroll
      for (int dt = 0; dt < 4; ++dt) {
        v8bf vf = *reinterpret_cast<const v8bf*>(&Vbuf[cur][(dt * 2 + ks) * 512 + lane * 8]);
        O[dt] = __builtin_amdgcn_mfma_f32_16x16x32_bf16(vf, pb, O[dt], 0, 0, 0);
      }
    }
  }

  // row sums for q=l15: reduce across the 4 quad groups
  ps += __shfl_xor(ps, 16);
  ps += __shfl_xor(ps, 32);
  const float inv = 1.f / ps;

  // O^T layout: lane holds q=l15, d = dt*16 + quad*4 + i -> packed b64 stores
  const int bb = bh >> 4, h = bh & 15;
  ushort_t* yp = yb + ((size_t)bb * Tc + s + l15) * Cc + h * Dc + quad * 4;
  #pragma unroll
  for (int dt = 0; dt < 4; ++dt) {
    uint2 pa;
    pa.x = pack2bf(O[dt][0] * inv, O[dt][1] * inv);
    pa.y = pack2bf(O[dt][2] * inv, O[dt][3] * inv);
    *reinterpret_cast<uint2*>(yp + dt * 16) = pa;
  }
}

// MFMA flash attention v12 (verified rounds 9): balanced sequential pairing
// (1024 blocks = 4/CU, uniform 33 iters) + LDS P-transform body. 40 KB LDS.
// XCD swizzle REVERTED: round 12 showed it cut FETCH 195->29 MB but bought
// no time (staging off critical path) and possibly cost ~4%.
__global__ __launch_bounds__(256, 4) void flash_mfma12(const ushort_t* __restrict__ Qb,
                                                       const ushort_t* __restrict__ Kb,
                                                       const ushort_t* __restrict__ Vt,
                                                       ushort_t* __restrict__ yb) {
  const int x = blockIdx.x;                    // 0..15
  const int bh = blockIdx.y;
  const int jqA = 31 - x;                      // long item: 31..16 (longest first)
  const int jqB = x;                           // short item: 0..15
  const int t = threadIdx.x;
  const int w = t >> 6;
  const int lane = t & 63;
  const int quad = lane >> 4;
  const int l15 = lane & 15;

  __shared__ __align__(16) ushort_t Kbuf[2][8 * 512];   // 8 chunks x 1KiB, x2
  __shared__ __align__(16) ushort_t Vbuf[2][8 * 512];
  __shared__ __align__(16) ushort_t Pbuf[4][1024];      // per-wave 2KB P scratch

  flash_body(jqA, bh, w, lane, quad, l15, Qb, Kb, Vt, yb, Kbuf, Vbuf, &Pbuf[w][0]);
  __syncthreads();   // item A fully done with LDS before item B's prologue writes
  flash_body(jqB, bh, w, lane, quad, l15, Qb, Kb, Vt, yb, Kbuf, Vbuf, &Pbuf[w][0]);
}

extern "C" void kernel_launch(void* const* d_in, const int* in_sizes, int n_in,
                              void* d_out, int out_size, void* d_ws, size_t ws_size,
                              hipStream_t stream) {
  const float* x      = (const float*)d_in[0];   // [B,T,C]
  const float* w_attn = (const float*)d_in[1];   // [C,3C]
  const float* b_attn = (const float*)d_in[2];   // [3C]
  const float* w_proj = (const float*)d_in[3];   // [C,C]
  const float* b_proj = (const float*)d_in[4];   // [C]
  float* out = (float*)d_out;                    // [B,T,C] fp32

  const int M = Bc * Tc;        // 8192
  const int K = Cc;             // 1024
  const int N_qkv = 3 * Cc;     // 3072

  ushort_t* xb     = (ushort_t*)d_ws;                     // M*K        (16 MB)
  ushort_t* wattnT = xb + (size_t)M * K;                  // 3C*C       (6 MB)
  ushort_t* wprojT = wattnT + (size_t)N_qkv * K;          // C*C        (2 MB)
  ushort_t* Qb     = wprojT + (size_t)Cc * Cc;            // [bh,t,d]   (16 MB)
  ushort_t* Kb     = Qb + (size_t)M * Cc;                 // [bh,t,d]   (16 MB)
  ushort_t* Vt     = Kb + (size_t)M * Cc;                 // [bh,d,t]   (16 MB)
  ushort_t* yb     = Vt + (size_t)M * Cc;                 // [m,C]      (16 MB)

  int nx = M * K;
  cvt_bf16<<<(nx / 8 + 255) / 256, 256, 0, stream>>>(x, xb, nx);
  transpose_bf16t<<<dim3(N_qkv / 64, K / 64), 256, 0, stream>>>(w_attn, wattnT, K, N_qkv);
  transpose_bf16t<<<dim3(Cc / 64, K / 64), 256, 0, stream>>>(w_proj, wprojT, K, Cc);

  // qkv = x @ w_attn + b_attn  -> Qb/Kb ([bh,t,d]) and Vt ([bh,d,t]) bf16
  gemm128<1><<<dim3(N_qkv / 128, M / 128), 256, 0, stream>>>(
      xb, wattnT, b_attn, nullptr, Qb, Kb, Vt, M, N_qkv, K);

  // y = softmax(QK^T/sqrt(D)) V  (balanced pairing + LDS P-transform flash)
  flash_mfma12<<<dim3(Tc / 128, Bc * Hc), 256, 0, stream>>>(Qb, Kb, Vt, yb);

  // out = y @ w_proj + b_proj   (fp32 out, 2-phase 128x128)
  gemm128<0><<<dim3(Cc / 128, M / 128), 256, 0, stream>>>(
      yb, wprojT, b_proj, out, nullptr, nullptr, nullptr, M, Cc, K);
}